// Round 1
// 806.231 us; speedup vs baseline: 1.0452x; 1.0452x over previous
//
#include <hip/hip_runtime.h>
#include <hip/hip_bf16.h>

#define C_    128
#define HW_   65536
#define B_    8
#define WIMG_ 256

typedef __attribute__((ext_vector_type(8))) short short8;
typedef __attribute__((ext_vector_type(4))) short short4b;
typedef __attribute__((ext_vector_type(4))) float floatx4;

static __device__ __forceinline__ short f2bf(float x) {
  __hip_bfloat16 h = __float2bfloat16(x);
  return *reinterpret_cast<short*>(&h);
}
static __device__ __forceinline__ int pack2(float a, float b) {
  return (int)(unsigned short)f2bf(a) | ((int)(unsigned short)f2bf(b) << 16);
}

// ---- Kernel 1: per-(b,c) mean/rstd over 65536 spatial elems ----
// Explicit 16-deep load batch: forces 16 outstanding loads/thread (MLP),
// the rolled loop was latency-bound at ~0.7 TB/s.
__global__ __launch_bounds__(1024) void ln_stats_kernel(const float* __restrict__ x,
                                                        float* __restrict__ stats) {
  const int bc = blockIdx.x;
  const float4* p4 = (const float4*)(x + (size_t)bc * HW_);
  float4 v[16];
  #pragma unroll
  for (int k = 0; k < 16; ++k) v[k] = p4[threadIdx.x + (k << 10)];
  float s = 0.f, ss = 0.f;
  #pragma unroll
  for (int k = 0; k < 16; ++k) {
    s  += (v[k].x + v[k].y) + (v[k].z + v[k].w);
    ss += (v[k].x * v[k].x + v[k].y * v[k].y) + (v[k].z * v[k].z + v[k].w * v[k].w);
  }
  #pragma unroll
  for (int off = 32; off > 0; off >>= 1) {
    s  += __shfl_down(s, off, 64);
    ss += __shfl_down(ss, off, 64);
  }
  __shared__ float red[32];
  const int wv = threadIdx.x >> 6;
  if ((threadIdx.x & 63) == 0) { red[wv * 2] = s; red[wv * 2 + 1] = ss; }
  __syncthreads();
  if (threadIdx.x == 0) {
    float S = 0.f, SS = 0.f;
    #pragma unroll
    for (int v2 = 0; v2 < 16; ++v2) { S += red[v2 * 2]; SS += red[v2 * 2 + 1]; }
    const float mean = S * (1.f / HW_);
    const float var  = SS * (1.f / HW_) - mean * mean;
    stats[bc * 2]     = mean;
    stats[bc * 2 + 1] = rsqrtf(var + 1e-6f);
  }
}

// ---- Kernel 2: fp32 -> bf16 weight conversion into workspace ----
// Q rows (first 128*128 elems of qkv_w) pre-scaled by 32^-0.5.
__global__ __launch_bounds__(256) void cvt_w_kernel(const float* __restrict__ qkv_w,
                                                    const float* __restrict__ proj_w,
                                                    short* __restrict__ dst) {
  const int i = blockIdx.x * 256 + threadIdx.x;        // 0..65535
  float v = (i < 49152) ? qkv_w[i] : proj_w[i - 49152];
  if (i < 16384) v *= 0.17677669529663687f;            // fold Q scale into weights
  dst[i] = f2bf(v);
}

// ---- Kernel 3: fused LN-apply + QKV + window attention + proj, MFMA ----
// One block per 8x8 window; wave w = head h. LDS re-aliased to 53248 B
// (was 70656) -> 3 blocks/CU instead of 2. Regions (bytes):
//   Xn  [64][136] bf16 @0      (17408)  normalized input, token-major
//   Qr  [64][136] bf16 @0      (alias Xn; written after post-GEMM barrier)
//   Kr  [64][136] bf16 @17408  (17408)
//   Vr  [128][72] bf16 @34816  (18432)  V d-major          -> total 53248
//   Pw  (per wave) [64][68] bf16 @ w*8704 — exactly fills Qr+Kr (dead)
//   Att [64][136] bf16 @0      — aliases Pw region (dead after PV reads)
__global__ __launch_bounds__(256, 3) void win_attn_kernel(
    const float* __restrict__ x, const float* __restrict__ stats,
    const float* __restrict__ norm_w, const float* __restrict__ norm_b,
    const short* __restrict__ wq, const float* __restrict__ qkv_b,
    const short* __restrict__ wp, const float* __restrict__ proj_b,
    float* __restrict__ out)
{
  __shared__ __align__(16) char lds[53248];
  short* Xn = (short*)lds;
  short* Qr = (short*)lds;                 // alias of Xn (see barrier below)
  short* Kr = (short*)(lds + 17408);
  short* Vr = (short*)(lds + 34816);

  const int tid = threadIdx.x;
  const int l15 = tid & 15;
  const int qd  = (tid >> 4) & 3;           // quad within wave
  const int w   = tid >> 6;                 // wave = head
  const int ww = blockIdx.x, wh = blockIdx.y, b = blockIdx.z;

  const float* xb = x + (size_t)b * C_ * HW_ + (size_t)(wh * 8) * WIMG_ + ww * 8;
  const float* st = stats + b * C_ * 2;

  // ---- Phase A: stage normalized window as bf16 Xn[t][c] ----
  {
    const int c = tid >> 1, half = tid & 1;
    const float aa = st[c * 2 + 1] * norm_w[c];
    const float bb = norm_b[c] - st[c * 2] * aa;
    const float* xc = xb + (size_t)c * HW_ + half * 4;
    float4 v[8];
    #pragma unroll
    for (int r = 0; r < 8; ++r) v[r] = *(const float4*)(xc + r * WIMG_);
    #pragma unroll
    for (int r = 0; r < 8; ++r) {
      const int t = r * 8 + half * 4;
      Xn[(t + 0) * 136 + c] = f2bf(v[r].x * aa + bb);
      Xn[(t + 1) * 136 + c] = f2bf(v[r].y * aa + bb);
      Xn[(t + 2) * 136 + c] = f2bf(v[r].z * aa + bb);
      Xn[(t + 3) * 136 + c] = f2bf(v[r].w * aa + bb);
    }
  }
  __syncthreads();

  const float scale = 0.17677669529663687f;   // 32^-0.5 (folded into wq/bias for Q)

  // ---- Phase B1: QKV GEMM, wave w computes output rows [w*96, w*96+96) ----
  floatx4 acc[6][4];
  const int ro = w * 96;
  {
    #pragma unroll
    for (int mt = 0; mt < 6; ++mt) {
      const bool isq = (ro + mt * 16) < 128;
      #pragma unroll
      for (int r = 0; r < 4; ++r) {
        float bias = qkv_b[ro + mt * 16 + qd * 4 + r];
        if (isq) bias *= scale;
        #pragma unroll
        for (int nt = 0; nt < 4; ++nt) acc[mt][nt][r] = bias;
      }
    }
    #pragma unroll
    for (int kb = 0; kb < 4; ++kb) {
      short8 bfr[4];
      #pragma unroll
      for (int nt = 0; nt < 4; ++nt)
        bfr[nt] = *(const short8*)&Xn[(nt * 16 + l15) * 136 + kb * 32 + qd * 8];
      #pragma unroll
      for (int mt = 0; mt < 6; ++mt) {
        short8 af = *(const short8*)&wq[(ro + mt * 16 + l15) * 128 + kb * 32 + qd * 8];
        #pragma unroll
        for (int nt = 0; nt < 4; ++nt)
          acc[mt][nt] = __builtin_amdgcn_mfma_f32_16x16x32_bf16(af, bfr[nt], acc[mt][nt], 0, 0, 0);
      }
    }
  }
  __syncthreads();   // all Xn reads done -> Qr (alias of Xn) may be written

  // ---- Phase B2: scatter QKV to LDS (Q/K token-major packed b32, V d-major) ----
  {
    #pragma unroll
    for (int mt = 0; mt < 6; ++mt) {
      const int ob = ro + mt * 16;            // wave-uniform
      #pragma unroll
      for (int nt = 0; nt < 4; ++nt) {
        const int t = nt * 16 + l15;
        floatx4 a = acc[mt][nt];
        if (ob < 128) {
          const int ol = ob + qd * 4;
          *(int*)&Qr[t * 136 + ol]     = pack2(a[0], a[1]);
          *(int*)&Qr[t * 136 + ol + 2] = pack2(a[2], a[3]);
        } else if (ob < 256) {
          const int ol = (ob - 128) + qd * 4;
          *(int*)&Kr[t * 136 + ol]     = pack2(a[0], a[1]);
          *(int*)&Kr[t * 136 + ol + 2] = pack2(a[2], a[3]);
        } else {
          const int o0 = (ob - 256) + qd * 4;
          #pragma unroll
          for (int r = 0; r < 4; ++r) Vr[(o0 + r) * 72 + t] = f2bf(a[r]);
        }
      }
    }
  }
  __syncthreads();

  // ---- Phase C: scores S = Q^T K + softmax (head h = w; scale pre-folded) ----
  const int h = w;
  floatx4 s[4][4];
  {
    short8 qa[4], ka[4];
    #pragma unroll
    for (int it = 0; it < 4; ++it)
      qa[it] = *(const short8*)&Qr[(it * 16 + l15) * 136 + h * 32 + qd * 8];
    #pragma unroll
    for (int jt = 0; jt < 4; ++jt)
      ka[jt] = *(const short8*)&Kr[(jt * 16 + l15) * 136 + h * 32 + qd * 8];
    const floatx4 z = {0.f, 0.f, 0.f, 0.f};
    #pragma unroll
    for (int it = 0; it < 4; ++it)
      #pragma unroll
      for (int jt = 0; jt < 4; ++jt)
        s[it][jt] = __builtin_amdgcn_mfma_f32_16x16x32_bf16(qa[it], ka[jt], z, 0, 0, 0);
  }
  float rs[4][4];                              // 1/rowsum, rows match PV C-layout
  #pragma unroll
  for (int it = 0; it < 4; ++it)
    #pragma unroll
    for (int r = 0; r < 4; ++r) {
      float m = fmaxf(fmaxf(s[it][0][r], s[it][1][r]), fmaxf(s[it][2][r], s[it][3][r]));
      m = fmaxf(m, __shfl_xor(m, 1)); m = fmaxf(m, __shfl_xor(m, 2));
      m = fmaxf(m, __shfl_xor(m, 4)); m = fmaxf(m, __shfl_xor(m, 8));
      float sm = 0.f;
      #pragma unroll
      for (int jt = 0; jt < 4; ++jt) { s[it][jt][r] = __expf(s[it][jt][r] - m); sm += s[it][jt][r]; }
      sm += __shfl_xor(sm, 1); sm += __shfl_xor(sm, 2);
      sm += __shfl_xor(sm, 4); sm += __shfl_xor(sm, 8);
      rs[it][r] = 1.f / sm;
    }
  __syncthreads();                             // Q/K frag reads done everywhere

  // ---- write P (unnormalized exp) to per-wave LDS [64][68] ----
  short* Pw = (short*)(lds + w * 8704);        // 4 waves * 8704 = 34816 (Qr+Kr, dead)
  #pragma unroll
  for (int it = 0; it < 4; ++it)
    #pragma unroll
    for (int jt = 0; jt < 4; ++jt)
      #pragma unroll
      for (int r = 0; r < 4; ++r)
        Pw[(it * 16 + qd * 4 + r) * 68 + jt * 16 + l15] = f2bf(s[it][jt][r]);
  __syncthreads();

  // ---- Phase D: O = P V (normalization folded into epilogue) ----
  floatx4 o[4][2];
  #pragma unroll
  for (int it = 0; it < 4; ++it)
    #pragma unroll
    for (int dt = 0; dt < 2; ++dt) o[it][dt] = (floatx4){0.f, 0.f, 0.f, 0.f};
  #pragma unroll
  for (int kb = 0; kb < 2; ++kb) {
    short8 pa[4], vb[2];
    #pragma unroll
    for (int it = 0; it < 4; ++it) {
      // stride 68 shorts is only 8B-aligned -> two b64 reads
      short4b plo = *(const short4b*)&Pw[(it * 16 + l15) * 68 + kb * 32 + qd * 8];
      short4b phi = *(const short4b*)&Pw[(it * 16 + l15) * 68 + kb * 32 + qd * 8 + 4];
      pa[it] = __builtin_shufflevector(plo, phi, 0, 1, 2, 3, 4, 5, 6, 7);
    }
    #pragma unroll
    for (int dt = 0; dt < 2; ++dt)
      vb[dt] = *(const short8*)&Vr[(h * 32 + dt * 16 + l15) * 72 + kb * 32 + qd * 8];
    #pragma unroll
    for (int it = 0; it < 4; ++it)
      #pragma unroll
      for (int dt = 0; dt < 2; ++dt)
        o[it][dt] = __builtin_amdgcn_mfma_f32_16x16x32_bf16(pa[it], vb[dt], o[it][dt], 0, 0, 0);
  }
  __syncthreads();                             // all P reads done -> region reusable

  // ---- Att[t][c] bf16 for proj (channel c = h*32+d) ----
  short* Att = (short*)lds;
  #pragma unroll
  for (int it = 0; it < 4; ++it)
    #pragma unroll
    for (int dt = 0; dt < 2; ++dt)
      #pragma unroll
      for (int r = 0; r < 4; ++r)
        Att[(it * 16 + qd * 4 + r) * 136 + h * 32 + dt * 16 + l15] = f2bf(o[it][dt][r] * rs[it][r]);
  __syncthreads();

  // ---- Phase E: proj GEMM, wave w computes output channels [w*32, w*32+32) ----
  {
    floatx4 pacc[2][4];
    #pragma unroll
    for (int mt = 0; mt < 2; ++mt)
      #pragma unroll
      for (int r = 0; r < 4; ++r) {
        const float bias = proj_b[w * 32 + mt * 16 + qd * 4 + r];
        #pragma unroll
        for (int nt = 0; nt < 4; ++nt) pacc[mt][nt][r] = bias;
      }
    #pragma unroll
    for (int kb = 0; kb < 4; ++kb) {
      short8 bfr[4];
      #pragma unroll
      for (int nt = 0; nt < 4; ++nt)
        bfr[nt] = *(const short8*)&Att[(nt * 16 + l15) * 136 + kb * 32 + qd * 8];
      #pragma unroll
      for (int mt = 0; mt < 2; ++mt) {
        short8 af = *(const short8*)&wp[(w * 32 + mt * 16 + l15) * 128 + kb * 32 + qd * 8];
        #pragma unroll
        for (int nt = 0; nt < 4; ++nt)
          pacc[mt][nt] = __builtin_amdgcn_mfma_f32_16x16x32_bf16(af, bfr[nt], pacc[mt][nt], 0, 0, 0);
      }
    }
    float* ob_ = out + (size_t)b * C_ * HW_ + (size_t)(wh * 8) * WIMG_ + ww * 8;
    #pragma unroll
    for (int mt = 0; mt < 2; ++mt)
      #pragma unroll
      for (int nt = 0; nt < 4; ++nt)
        #pragma unroll
        for (int r = 0; r < 4; ++r) {
          const int oc = w * 32 + mt * 16 + qd * 4 + r;
          const int t  = nt * 16 + l15;
          ob_[(size_t)oc * HW_ + (t >> 3) * WIMG_ + (t & 7)] = pacc[mt][nt][r];
        }
  }
}

extern "C" void kernel_launch(void* const* d_in, const int* in_sizes, int n_in,
                              void* d_out, int out_size, void* d_ws, size_t ws_size,
                              hipStream_t stream) {
  const float* x      = (const float*)d_in[0];
  const float* norm_w = (const float*)d_in[1];
  const float* norm_b = (const float*)d_in[2];
  const float* qkv_w  = (const float*)d_in[3];
  const float* qkv_b  = (const float*)d_in[4];
  const float* proj_w = (const float*)d_in[5];
  const float* proj_b = (const float*)d_in[6];
  float* out   = (float*)d_out;
  float* stats = (float*)d_ws;                         // 1024*2 f32 = 8 KB
  short* wq    = (short*)((char*)d_ws + 8192);         // 384*128 bf16
  short* wp    = wq + 384 * 128;                       // 128*128 bf16

  hipLaunchKernelGGL(cvt_w_kernel, dim3(256), dim3(256), 0, stream, qkv_w, proj_w, wq);
  hipLaunchKernelGGL(ln_stats_kernel, dim3(B_ * C_), dim3(1024), 0, stream, x, stats);
  hipLaunchKernelGGL(win_attn_kernel, dim3(32, 32, B_), dim3(256), 0, stream,
                     x, stats, norm_w, norm_b, wq, qkv_b, wp, proj_b, out);
}

// Round 2
// 716.421 us; speedup vs baseline: 1.1762x; 1.1254x over previous
//
#include <hip/hip_runtime.h>
#include <hip/hip_bf16.h>

#define C_    128
#define HW_   65536
#define B_    8
#define WIMG_ 256

typedef __attribute__((ext_vector_type(8))) short short8;
typedef __attribute__((ext_vector_type(4))) short short4b;
typedef __attribute__((ext_vector_type(4))) float floatx4;

static __device__ __forceinline__ short f2bf(float x) {
  __hip_bfloat16 h = __float2bfloat16(x);
  return *reinterpret_cast<short*>(&h);
}
static __device__ __forceinline__ int pack2(float a, float b) {
  return (int)(unsigned short)f2bf(a) | ((int)(unsigned short)f2bf(b) << 16);
}

// ---- Kernel 1: per-(b,c) mean/rstd over 65536 spatial elems ----
// XCD-affine: dispatch round-robins XCDs (bid%8); remap so XCD x reads a
// contiguous 32MB image (bc = x*128 + bid/8) -> sequential DRAM stream/XCD.
__global__ __launch_bounds__(1024) void ln_stats_kernel(const float* __restrict__ x,
                                                        float* __restrict__ stats) {
  const int bc = ((blockIdx.x & 7) << 7) + (blockIdx.x >> 3);
  const float4* p4 = (const float4*)(x + (size_t)bc * HW_);
  float4 v[16];
  #pragma unroll
  for (int k = 0; k < 16; ++k) v[k] = p4[threadIdx.x + (k << 10)];
  float s = 0.f, ss = 0.f;
  #pragma unroll
  for (int k = 0; k < 16; ++k) {
    s  += (v[k].x + v[k].y) + (v[k].z + v[k].w);
    ss += (v[k].x * v[k].x + v[k].y * v[k].y) + (v[k].z * v[k].z + v[k].w * v[k].w);
  }
  #pragma unroll
  for (int off = 32; off > 0; off >>= 1) {
    s  += __shfl_down(s, off, 64);
    ss += __shfl_down(ss, off, 64);
  }
  __shared__ float red[32];
  const int wv = threadIdx.x >> 6;
  if ((threadIdx.x & 63) == 0) { red[wv * 2] = s; red[wv * 2 + 1] = ss; }
  __syncthreads();
  if (threadIdx.x == 0) {
    float S = 0.f, SS = 0.f;
    #pragma unroll
    for (int v2 = 0; v2 < 16; ++v2) { S += red[v2 * 2]; SS += red[v2 * 2 + 1]; }
    const float mean = S * (1.f / HW_);
    const float var  = SS * (1.f / HW_) - mean * mean;
    stats[bc * 2]     = mean;
    stats[bc * 2 + 1] = rsqrtf(var + 1e-6f);
  }
}

// ---- Kernel 2: fp32 -> bf16 weight conversion into workspace ----
// Q rows (first 128*128 elems of qkv_w) pre-scaled by 32^-0.5.
__global__ __launch_bounds__(256) void cvt_w_kernel(const float* __restrict__ qkv_w,
                                                    const float* __restrict__ proj_w,
                                                    short* __restrict__ dst) {
  const int i = blockIdx.x * 256 + threadIdx.x;        // 0..65535
  float v = (i < 49152) ? qkv_w[i] : proj_w[i - 49152];
  if (i < 16384) v *= 0.17677669529663687f;            // fold Q scale into weights
  dst[i] = f2bf(v);
}

// ---- Kernel 3: fused LN-apply + QKV + window attention + proj, MFMA ----
// One block per 8x8 window; wave w = head h. LDS 53248 B -> 3 blocks/CU.
// XCD-affine remap: XCD x owns image b=x; strips (wh) in order, ww fastest.
// The 32 blocks of a strip run concurrently on one XCD's 32 CUs, so the two
// 32B halves of every 64B x-line (ww and ww+1) merge in that XCD's L2.
__global__ __launch_bounds__(256, 3) void win_attn_kernel(
    const float* __restrict__ x, const float* __restrict__ stats,
    const float* __restrict__ norm_w, const float* __restrict__ norm_b,
    const short* __restrict__ wq, const float* __restrict__ qkv_b,
    const short* __restrict__ wp, const float* __restrict__ proj_b,
    float* __restrict__ out)
{
  __shared__ __align__(16) char lds[53248];
  short* Xn = (short*)lds;
  short* Qr = (short*)lds;                 // alias of Xn (see barrier below)
  short* Kr = (short*)(lds + 17408);
  short* Vr = (short*)(lds + 34816);

  const int tid = threadIdx.x;
  const int l15 = tid & 15;
  const int qd  = (tid >> 4) & 3;           // quad within wave
  const int w   = tid >> 6;                 // wave = head

  // XCD-contiguous work id: dispatch id bid runs on XCD bid%8 (round-robin);
  // work W = (bid%8)*1024 + bid/8 gives each XCD a contiguous strip range.
  const int bid = blockIdx.x;
  const int W   = ((bid & 7) << 10) + (bid >> 3);
  const int ww  = W & 31;
  const int wh  = (W >> 5) & 31;
  const int b   = W >> 10;

  const float* xb = x + (size_t)b * C_ * HW_ + (size_t)(wh * 8) * WIMG_ + ww * 8;
  const float* st = stats + b * C_ * 2;

  // ---- Phase A: stage normalized window as bf16 Xn[t][c] ----
  {
    const int c = tid >> 1, half = tid & 1;
    const float aa = st[c * 2 + 1] * norm_w[c];
    const float bb = norm_b[c] - st[c * 2] * aa;
    const float* xc = xb + (size_t)c * HW_ + half * 4;
    float4 v[8];
    #pragma unroll
    for (int r = 0; r < 8; ++r) v[r] = *(const float4*)(xc + r * WIMG_);
    #pragma unroll
    for (int r = 0; r < 8; ++r) {
      const int t = r * 8 + half * 4;
      Xn[(t + 0) * 136 + c] = f2bf(v[r].x * aa + bb);
      Xn[(t + 1) * 136 + c] = f2bf(v[r].y * aa + bb);
      Xn[(t + 2) * 136 + c] = f2bf(v[r].z * aa + bb);
      Xn[(t + 3) * 136 + c] = f2bf(v[r].w * aa + bb);
    }
  }
  __syncthreads();

  const float scale = 0.17677669529663687f;   // 32^-0.5 (folded into wq/bias for Q)

  // ---- Phase B1: QKV GEMM, wave w computes output rows [w*96, w*96+96) ----
  floatx4 acc[6][4];
  const int ro = w * 96;
  {
    #pragma unroll
    for (int mt = 0; mt < 6; ++mt) {
      const bool isq = (ro + mt * 16) < 128;
      #pragma unroll
      for (int r = 0; r < 4; ++r) {
        float bias = qkv_b[ro + mt * 16 + qd * 4 + r];
        if (isq) bias *= scale;
        #pragma unroll
        for (int nt = 0; nt < 4; ++nt) acc[mt][nt][r] = bias;
      }
    }
    #pragma unroll
    for (int kb = 0; kb < 4; ++kb) {
      short8 bfr[4];
      #pragma unroll
      for (int nt = 0; nt < 4; ++nt)
        bfr[nt] = *(const short8*)&Xn[(nt * 16 + l15) * 136 + kb * 32 + qd * 8];
      #pragma unroll
      for (int mt = 0; mt < 6; ++mt) {
        short8 af = *(const short8*)&wq[(ro + mt * 16 + l15) * 128 + kb * 32 + qd * 8];
        #pragma unroll
        for (int nt = 0; nt < 4; ++nt)
          acc[mt][nt] = __builtin_amdgcn_mfma_f32_16x16x32_bf16(af, bfr[nt], acc[mt][nt], 0, 0, 0);
      }
    }
  }
  __syncthreads();   // all Xn reads done -> Qr (alias of Xn) may be written

  // ---- Phase B2: scatter QKV to LDS (Q/K token-major packed b32, V d-major) ----
  {
    #pragma unroll
    for (int mt = 0; mt < 6; ++mt) {
      const int ob = ro + mt * 16;            // wave-uniform
      #pragma unroll
      for (int nt = 0; nt < 4; ++nt) {
        const int t = nt * 16 + l15;
        floatx4 a = acc[mt][nt];
        if (ob < 128) {
          const int ol = ob + qd * 4;
          *(int*)&Qr[t * 136 + ol]     = pack2(a[0], a[1]);
          *(int*)&Qr[t * 136 + ol + 2] = pack2(a[2], a[3]);
        } else if (ob < 256) {
          const int ol = (ob - 128) + qd * 4;
          *(int*)&Kr[t * 136 + ol]     = pack2(a[0], a[1]);
          *(int*)&Kr[t * 136 + ol + 2] = pack2(a[2], a[3]);
        } else {
          const int o0 = (ob - 256) + qd * 4;
          #pragma unroll
          for (int r = 0; r < 4; ++r) Vr[(o0 + r) * 72 + t] = f2bf(a[r]);
        }
      }
    }
  }
  __syncthreads();

  // ---- Phase C: scores S = Q^T K + softmax (head h = w; scale pre-folded) ----
  const int h = w;
  floatx4 s[4][4];
  {
    short8 qa[4], ka[4];
    #pragma unroll
    for (int it = 0; it < 4; ++it)
      qa[it] = *(const short8*)&Qr[(it * 16 + l15) * 136 + h * 32 + qd * 8];
    #pragma unroll
    for (int jt = 0; jt < 4; ++jt)
      ka[jt] = *(const short8*)&Kr[(jt * 16 + l15) * 136 + h * 32 + qd * 8];
    const floatx4 z = {0.f, 0.f, 0.f, 0.f};
    #pragma unroll
    for (int it = 0; it < 4; ++it)
      #pragma unroll
      for (int jt = 0; jt < 4; ++jt)
        s[it][jt] = __builtin_amdgcn_mfma_f32_16x16x32_bf16(qa[it], ka[jt], z, 0, 0, 0);
  }
  float rs[4][4];                              // 1/rowsum, rows match PV C-layout
  #pragma unroll
  for (int it = 0; it < 4; ++it)
    #pragma unroll
    for (int r = 0; r < 4; ++r) {
      float m = fmaxf(fmaxf(s[it][0][r], s[it][1][r]), fmaxf(s[it][2][r], s[it][3][r]));
      m = fmaxf(m, __shfl_xor(m, 1)); m = fmaxf(m, __shfl_xor(m, 2));
      m = fmaxf(m, __shfl_xor(m, 4)); m = fmaxf(m, __shfl_xor(m, 8));
      float sm = 0.f;
      #pragma unroll
      for (int jt = 0; jt < 4; ++jt) { s[it][jt][r] = __expf(s[it][jt][r] - m); sm += s[it][jt][r]; }
      sm += __shfl_xor(sm, 1); sm += __shfl_xor(sm, 2);
      sm += __shfl_xor(sm, 4); sm += __shfl_xor(sm, 8);
      rs[it][r] = 1.f / sm;
    }
  __syncthreads();                             // Q/K frag reads done everywhere

  // ---- write P (unnormalized exp) to per-wave LDS [64][68] ----
  short* Pw = (short*)(lds + w * 8704);        // 4 waves * 8704 = 34816 (Qr+Kr, dead)
  #pragma unroll
  for (int it = 0; it < 4; ++it)
    #pragma unroll
    for (int jt = 0; jt < 4; ++jt)
      #pragma unroll
      for (int r = 0; r < 4; ++r)
        Pw[(it * 16 + qd * 4 + r) * 68 + jt * 16 + l15] = f2bf(s[it][jt][r]);
  __syncthreads();

  // ---- Phase D: O = P V (normalization folded into epilogue) ----
  floatx4 o[4][2];
  #pragma unroll
  for (int it = 0; it < 4; ++it)
    #pragma unroll
    for (int dt = 0; dt < 2; ++dt) o[it][dt] = (floatx4){0.f, 0.f, 0.f, 0.f};
  #pragma unroll
  for (int kb = 0; kb < 2; ++kb) {
    short8 pa[4], vb[2];
    #pragma unroll
    for (int it = 0; it < 4; ++it) {
      // stride 68 shorts is only 8B-aligned -> two b64 reads
      short4b plo = *(const short4b*)&Pw[(it * 16 + l15) * 68 + kb * 32 + qd * 8];
      short4b phi = *(const short4b*)&Pw[(it * 16 + l15) * 68 + kb * 32 + qd * 8 + 4];
      pa[it] = __builtin_shufflevector(plo, phi, 0, 1, 2, 3, 4, 5, 6, 7);
    }
    #pragma unroll
    for (int dt = 0; dt < 2; ++dt)
      vb[dt] = *(const short8*)&Vr[(h * 32 + dt * 16 + l15) * 72 + kb * 32 + qd * 8];
    #pragma unroll
    for (int it = 0; it < 4; ++it)
      #pragma unroll
      for (int dt = 0; dt < 2; ++dt)
        o[it][dt] = __builtin_amdgcn_mfma_f32_16x16x32_bf16(pa[it], vb[dt], o[it][dt], 0, 0, 0);
  }
  __syncthreads();                             // all P reads done -> region reusable

  // ---- Att[t][c] bf16 for proj (channel c = h*32+d) ----
  short* Att = (short*)lds;
  #pragma unroll
  for (int it = 0; it < 4; ++it)
    #pragma unroll
    for (int dt = 0; dt < 2; ++dt)
      #pragma unroll
      for (int r = 0; r < 4; ++r)
        Att[(it * 16 + qd * 4 + r) * 136 + h * 32 + dt * 16 + l15] = f2bf(o[it][dt][r] * rs[it][r]);
  __syncthreads();

  // ---- Phase E: proj GEMM, wave w computes output channels [w*32, w*32+32) ----
  {
    floatx4 pacc[2][4];
    #pragma unroll
    for (int mt = 0; mt < 2; ++mt)
      #pragma unroll
      for (int r = 0; r < 4; ++r) {
        const float bias = proj_b[w * 32 + mt * 16 + qd * 4 + r];
        #pragma unroll
        for (int nt = 0; nt < 4; ++nt) pacc[mt][nt][r] = bias;
      }
    #pragma unroll
    for (int kb = 0; kb < 4; ++kb) {
      short8 bfr[4];
      #pragma unroll
      for (int nt = 0; nt < 4; ++nt)
        bfr[nt] = *(const short8*)&Att[(nt * 16 + l15) * 136 + kb * 32 + qd * 8];
      #pragma unroll
      for (int mt = 0; mt < 2; ++mt) {
        short8 af = *(const short8*)&wp[(w * 32 + mt * 16 + l15) * 128 + kb * 32 + qd * 8];
        #pragma unroll
        for (int nt = 0; nt < 4; ++nt)
          pacc[mt][nt] = __builtin_amdgcn_mfma_f32_16x16x32_bf16(af, bfr[nt], pacc[mt][nt], 0, 0, 0);
      }
    }
    float* ob_ = out + (size_t)b * C_ * HW_ + (size_t)(wh * 8) * WIMG_ + ww * 8;
    #pragma unroll
    for (int mt = 0; mt < 2; ++mt)
      #pragma unroll
      for (int nt = 0; nt < 4; ++nt)
        #pragma unroll
        for (int r = 0; r < 4; ++r) {
          const int oc = w * 32 + mt * 16 + qd * 4 + r;
          const int t  = nt * 16 + l15;
          ob_[(size_t)oc * HW_ + (t >> 3) * WIMG_ + (t & 7)] = pacc[mt][nt][r];
        }
  }
}

extern "C" void kernel_launch(void* const* d_in, const int* in_sizes, int n_in,
                              void* d_out, int out_size, void* d_ws, size_t ws_size,
                              hipStream_t stream) {
  const float* x      = (const float*)d_in[0];
  const float* norm_w = (const float*)d_in[1];
  const float* norm_b = (const float*)d_in[2];
  const float* qkv_w  = (const float*)d_in[3];
  const float* qkv_b  = (const float*)d_in[4];
  const float* proj_w = (const float*)d_in[5];
  const float* proj_b = (const float*)d_in[6];
  float* out   = (float*)d_out;
  float* stats = (float*)d_ws;                         // 1024*2 f32 = 8 KB
  short* wq    = (short*)((char*)d_ws + 8192);         // 384*128 bf16
  short* wp    = wq + 384 * 128;                       // 128*128 bf16

  hipLaunchKernelGGL(cvt_w_kernel, dim3(256), dim3(256), 0, stream, qkv_w, proj_w, wq);
  hipLaunchKernelGGL(ln_stats_kernel, dim3(B_ * C_), dim3(1024), 0, stream, x, stats);
  hipLaunchKernelGGL(win_attn_kernel, dim3(32 * 32 * B_), dim3(256), 0, stream,
                     x, stats, norm_w, norm_b, wq, qkv_b, wp, proj_b, out);
}

// Round 3
// 673.240 us; speedup vs baseline: 1.2517x; 1.0641x over previous
//
#include <hip/hip_runtime.h>
#include <hip/hip_bf16.h>

#define C_    128
#define HW_   65536
#define B_    8
#define WIMG_ 256

typedef __attribute__((ext_vector_type(8))) short short8;
typedef __attribute__((ext_vector_type(4))) float floatx4;

static __device__ __forceinline__ short f2bf(float x) {
  __hip_bfloat16 h = __float2bfloat16(x);
  return *reinterpret_cast<short*>(&h);
}
static __device__ __forceinline__ int pack2(float a, float b) {
  return (int)(unsigned short)f2bf(a) | ((int)(unsigned short)f2bf(b) << 16);
}

// DPP row-rotate reduce helpers (16-lane row = one qd-group): VALU pipe, no LDS.
template<int CTRL>
static __device__ __forceinline__ float fmax_dpp(float x) {
  int p = __builtin_amdgcn_update_dpp(0, __builtin_bit_cast(int, x), CTRL, 0xF, 0xF, true);
  return fmaxf(x, __builtin_bit_cast(float, p));
}
template<int CTRL>
static __device__ __forceinline__ float fadd_dpp(float x) {
  int p = __builtin_amdgcn_update_dpp(0, __builtin_bit_cast(int, x), CTRL, 0xF, 0xF, true);
  return x + __builtin_bit_cast(float, p);
}

// ---- Kernel 1a: partial sums, one block per contiguous 32KB chunk ----
// 8192 blocks x 256 threads; XCD-affine (XCD x streams a contiguous 32MB).
__global__ __launch_bounds__(256) void ln_part_kernel(const float* __restrict__ x,
                                                      float2* __restrict__ part) {
  const int cid = ((blockIdx.x & 7) << 10) | (blockIdx.x >> 3);
  const float4* p4 = (const float4*)(x + (size_t)cid * 8192);
  float4 v[8];
  #pragma unroll
  for (int k = 0; k < 8; ++k) v[k] = p4[threadIdx.x + (k << 8)];
  float s = 0.f, ss = 0.f;
  #pragma unroll
  for (int k = 0; k < 8; ++k) {
    s  += (v[k].x + v[k].y) + (v[k].z + v[k].w);
    ss += (v[k].x * v[k].x + v[k].y * v[k].y) + (v[k].z * v[k].z + v[k].w * v[k].w);
  }
  #pragma unroll
  for (int off = 32; off > 0; off >>= 1) {
    s  += __shfl_down(s, off, 64);
    ss += __shfl_down(ss, off, 64);
  }
  __shared__ float red[8];
  const int wv = threadIdx.x >> 6;
  if ((threadIdx.x & 63) == 0) { red[wv * 2] = s; red[wv * 2 + 1] = ss; }
  __syncthreads();
  if (threadIdx.x == 0) {
    float S = red[0] + red[2] + red[4] + red[6];
    float SS = red[1] + red[3] + red[5] + red[7];
    part[cid] = make_float2(S, SS);
  }
}

// ---- Kernel 1b: finalize stats (1024 threads total) ----
__global__ __launch_bounds__(256) void ln_final_kernel(const float2* __restrict__ part,
                                                       float* __restrict__ stats) {
  const int bc = blockIdx.x * 256 + threadIdx.x;   // 0..1023
  float S = 0.f, SS = 0.f;
  #pragma unroll
  for (int k = 0; k < 8; ++k) { float2 p = part[bc * 8 + k]; S += p.x; SS += p.y; }
  const float mean = S * (1.f / HW_);
  const float var  = SS * (1.f / HW_) - mean * mean;
  stats[bc * 2]     = mean;
  stats[bc * 2 + 1] = rsqrtf(var + 1e-6f);
}

// ---- Kernel 2: fp32 -> bf16 weight conversion into workspace ----
// Q rows pre-scaled by 32^-0.5 * log2(e) so softmax uses exp2 directly.
__global__ __launch_bounds__(256) void cvt_w_kernel(const float* __restrict__ qkv_w,
                                                    const float* __restrict__ proj_w,
                                                    short* __restrict__ dst) {
  const int i = blockIdx.x * 256 + threadIdx.x;        // 0..65535
  float v = (i < 49152) ? qkv_w[i] : proj_w[i - 49152];
  if (i < 16384) v *= 0.17677669529663687f * 1.4426950408889634f;
  dst[i] = f2bf(v);
}

// ---- Kernel 3: fused LN-apply + QKV + window attention + proj, MFMA ----
// One block per 8x8 window; wave w = head h. LDS 53248 B -> 3 blocks/CU.
// Layout (bytes):
//   Xn  [64][136] bf16 @0      (17408)  normalized input (phase A/B1 only)
//   QK  [64][272] bf16 @0      (34816)  Q cols 0..127, K cols 136..263
//   Vr  [128][72] bf16 @34816  (18432)  V d-major
// P-tile of wave w overwrites wave w's OWN Q/K columns [w*32,w*32+32) and
// [136+w*32, ...) -> no cross-wave hazard -> 5 barriers instead of 7.
__global__ __launch_bounds__(256, 3) void win_attn_kernel(
    const float* __restrict__ x, const float* __restrict__ stats,
    const float* __restrict__ norm_w, const float* __restrict__ norm_b,
    const short* __restrict__ wq, const float* __restrict__ qkv_b,
    const short* __restrict__ wp, const float* __restrict__ proj_b,
    float* __restrict__ out)
{
  __shared__ __align__(16) char lds[53248];
  short* Xn = (short*)lds;
  short* QK = (short*)lds;                 // [64][272], written after B1 barrier
  short* Vr = (short*)(lds + 34816);

  const int tid = threadIdx.x;
  const int l15 = tid & 15;
  const int qd  = (tid >> 4) & 3;           // quad within wave
  const int w   = tid >> 6;                 // wave = head

  // XCD-contiguous work id (dispatch round-robins XCDs by blockIdx).
  const int bid = blockIdx.x;
  const int W   = ((bid & 7) << 10) + (bid >> 3);
  const int ww  = W & 31;
  const int wh  = (W >> 5) & 31;
  const int b   = W >> 10;

  const float* xb = x + (size_t)b * C_ * HW_ + (size_t)(wh * 8) * WIMG_ + ww * 8;
  const float* st = stats + b * C_ * 2;

  // ---- Phase A: stage normalized window as bf16 Xn[t][c] ----
  {
    const int c = tid >> 1, half = tid & 1;
    const float aa = st[c * 2 + 1] * norm_w[c];
    const float bb = norm_b[c] - st[c * 2] * aa;
    const float* xc = xb + (size_t)c * HW_ + half * 4;
    float4 v[8];
    #pragma unroll
    for (int r = 0; r < 8; ++r) v[r] = *(const float4*)(xc + r * WIMG_);
    #pragma unroll
    for (int r = 0; r < 8; ++r) {
      const int t = r * 8 + half * 4;
      Xn[(t + 0) * 136 + c] = f2bf(v[r].x * aa + bb);
      Xn[(t + 1) * 136 + c] = f2bf(v[r].y * aa + bb);
      Xn[(t + 2) * 136 + c] = f2bf(v[r].z * aa + bb);
      Xn[(t + 3) * 136 + c] = f2bf(v[r].w * aa + bb);
    }
  }
  __syncthreads();                                   // (1)

  // ---- Phase B1: QKV GEMM, wave w computes output rows [w*96, w*96+96) ----
  floatx4 acc[6][4];
  const int ro = w * 96;
  {
    #pragma unroll
    for (int mt = 0; mt < 6; ++mt) {
      const bool isq = (ro + mt * 16) < 128;
      #pragma unroll
      for (int r = 0; r < 4; ++r) {
        float bias = qkv_b[ro + mt * 16 + qd * 4 + r];
        if (isq) bias *= 0.17677669529663687f * 1.4426950408889634f;
        #pragma unroll
        for (int nt = 0; nt < 4; ++nt) acc[mt][nt][r] = bias;
      }
    }
    #pragma unroll
    for (int kb = 0; kb < 4; ++kb) {
      short8 bfr[4];
      #pragma unroll
      for (int nt = 0; nt < 4; ++nt)
        bfr[nt] = *(const short8*)&Xn[(nt * 16 + l15) * 136 + kb * 32 + qd * 8];
      #pragma unroll
      for (int mt = 0; mt < 6; ++mt) {
        short8 af = *(const short8*)&wq[(ro + mt * 16 + l15) * 128 + kb * 32 + qd * 8];
        #pragma unroll
        for (int nt = 0; nt < 4; ++nt)
          acc[mt][nt] = __builtin_amdgcn_mfma_f32_16x16x32_bf16(af, bfr[nt], acc[mt][nt], 0, 0, 0);
      }
    }
  }
  __syncthreads();   // (2) all Xn reads done -> QK (alias of Xn) may be written

  // ---- Phase B2: scatter QKV to LDS (Q/K token-major packed b32, V d-major) ----
  {
    #pragma unroll
    for (int mt = 0; mt < 6; ++mt) {
      const int ob = ro + mt * 16;            // wave-uniform
      #pragma unroll
      for (int nt = 0; nt < 4; ++nt) {
        const int t = nt * 16 + l15;
        floatx4 a = acc[mt][nt];
        if (ob < 128) {
          const int ol = ob + qd * 4;
          *(int*)&QK[t * 272 + ol]     = pack2(a[0], a[1]);
          *(int*)&QK[t * 272 + ol + 2] = pack2(a[2], a[3]);
        } else if (ob < 256) {
          const int ol = 136 + (ob - 128) + qd * 4;
          *(int*)&QK[t * 272 + ol]     = pack2(a[0], a[1]);
          *(int*)&QK[t * 272 + ol + 2] = pack2(a[2], a[3]);
        } else {
          const int o0 = (ob - 256) + qd * 4;
          #pragma unroll
          for (int r = 0; r < 4; ++r) Vr[(o0 + r) * 72 + t] = f2bf(a[r]);
        }
      }
    }
  }
  __syncthreads();                                   // (3)

  // ---- Phase C: scores (log2-domain, Q pre-scaled) + softmax via exp2 ----
  const int h = w;
  floatx4 s[4][4];
  {
    short8 qa[4], ka[4];
    #pragma unroll
    for (int it = 0; it < 4; ++it)
      qa[it] = *(const short8*)&QK[(it * 16 + l15) * 272 + h * 32 + qd * 8];
    #pragma unroll
    for (int jt = 0; jt < 4; ++jt)
      ka[jt] = *(const short8*)&QK[(jt * 16 + l15) * 272 + 136 + h * 32 + qd * 8];
    const floatx4 z = {0.f, 0.f, 0.f, 0.f};
    #pragma unroll
    for (int it = 0; it < 4; ++it)
      #pragma unroll
      for (int jt = 0; jt < 4; ++jt)
        s[it][jt] = __builtin_amdgcn_mfma_f32_16x16x32_bf16(qa[it], ka[jt], z, 0, 0, 0);
  }
  float rs[4][4];                              // 1/rowsum, rows match PV C-layout
  #pragma unroll
  for (int it = 0; it < 4; ++it)
    #pragma unroll
    for (int r = 0; r < 4; ++r) {
      float m = fmaxf(fmaxf(s[it][0][r], s[it][1][r]), fmaxf(s[it][2][r], s[it][3][r]));
      m = fmax_dpp<0x128>(m); m = fmax_dpp<0x124>(m);   // row_ror:8, :4
      m = fmax_dpp<0x122>(m); m = fmax_dpp<0x121>(m);   // row_ror:2, :1
      float sm = 0.f;
      #pragma unroll
      for (int jt = 0; jt < 4; ++jt) {
        s[it][jt][r] = __builtin_amdgcn_exp2f(s[it][jt][r] - m);
        sm += s[it][jt][r];
      }
      sm = fadd_dpp<0x128>(sm); sm = fadd_dpp<0x124>(sm);
      sm = fadd_dpp<0x122>(sm); sm = fadd_dpp<0x121>(sm);
      rs[it][r] = 1.f / sm;
    }

  // ---- write P into wave w's OWN Q/K columns (no barrier needed) ----
  // P[q=it*16+qd*4+r][j=jt*16+l15]: j<32 -> Q col w*32+j ; j>=32 -> K col 136+w*32+(j-32)
  #pragma unroll
  for (int it = 0; it < 4; ++it)
    #pragma unroll
    for (int jt = 0; jt < 4; ++jt) {
      const int col = ((jt < 2) ? (w * 32 + jt * 16) : (104 + w * 32 + jt * 16)) + l15;
      #pragma unroll
      for (int r = 0; r < 4; ++r)
        QK[(it * 16 + qd * 4 + r) * 272 + col] = f2bf(s[it][jt][r]);
    }
  // same-wave DS ordering guarantees P visibility for phase D reads

  // ---- Phase D: O = P V (normalization folded into epilogue) ----
  floatx4 o[4][2];
  #pragma unroll
  for (int it = 0; it < 4; ++it)
    #pragma unroll
    for (int dt = 0; dt < 2; ++dt) o[it][dt] = (floatx4){0.f, 0.f, 0.f, 0.f};
  #pragma unroll
  for (int kb = 0; kb < 2; ++kb) {
    const int pcol = (kb == 0) ? (w * 32 + qd * 8) : (136 + w * 32 + qd * 8);
    short8 pa[4], vb[2];
    #pragma unroll
    for (int it = 0; it < 4; ++it)
      pa[it] = *(const short8*)&QK[(it * 16 + l15) * 272 + pcol];
    #pragma unroll
    for (int dt = 0; dt < 2; ++dt)
      vb[dt] = *(const short8*)&Vr[(h * 32 + dt * 16 + l15) * 72 + kb * 32 + qd * 8];
    #pragma unroll
    for (int it = 0; it < 4; ++it)
      #pragma unroll
      for (int dt = 0; dt < 2; ++dt)
        o[it][dt] = __builtin_amdgcn_mfma_f32_16x16x32_bf16(pa[it], vb[dt], o[it][dt], 0, 0, 0);
  }
  __syncthreads();   // (4) all P reads done -> rows 0-31 (Att region) reusable

  // ---- Att[t][c] bf16 for proj (channel c = h*32+d) ----
  short* Att = (short*)lds;
  #pragma unroll
  for (int it = 0; it < 4; ++it)
    #pragma unroll
    for (int dt = 0; dt < 2; ++dt)
      #pragma unroll
      for (int r = 0; r < 4; ++r)
        Att[(it * 16 + qd * 4 + r) * 136 + h * 32 + dt * 16 + l15] = f2bf(o[it][dt][r] * rs[it][r]);
  __syncthreads();                                   // (5)

  // ---- Phase E: proj GEMM, wave w computes output channels [w*32, w*32+32) ----
  {
    floatx4 pacc[2][4];
    #pragma unroll
    for (int mt = 0; mt < 2; ++mt)
      #pragma unroll
      for (int r = 0; r < 4; ++r) {
        const float bias = proj_b[w * 32 + mt * 16 + qd * 4 + r];
        #pragma unroll
        for (int nt = 0; nt < 4; ++nt) pacc[mt][nt][r] = bias;
      }
    #pragma unroll
    for (int kb = 0; kb < 4; ++kb) {
      short8 bfr[4];
      #pragma unroll
      for (int nt = 0; nt < 4; ++nt)
        bfr[nt] = *(const short8*)&Att[(nt * 16 + l15) * 136 + kb * 32 + qd * 8];
      #pragma unroll
      for (int mt = 0; mt < 2; ++mt) {
        short8 af = *(const short8*)&wp[(w * 32 + mt * 16 + l15) * 128 + kb * 32 + qd * 8];
        #pragma unroll
        for (int nt = 0; nt < 4; ++nt)
          pacc[mt][nt] = __builtin_amdgcn_mfma_f32_16x16x32_bf16(af, bfr[nt], pacc[mt][nt], 0, 0, 0);
      }
    }
    float* ob_ = out + (size_t)b * C_ * HW_ + (size_t)(wh * 8) * WIMG_ + ww * 8;
    #pragma unroll
    for (int mt = 0; mt < 2; ++mt)
      #pragma unroll
      for (int nt = 0; nt < 4; ++nt)
        #pragma unroll
        for (int r = 0; r < 4; ++r) {
          const int oc = w * 32 + mt * 16 + qd * 4 + r;
          const int t  = nt * 16 + l15;
          ob_[(size_t)oc * HW_ + (t >> 3) * WIMG_ + (t & 7)] = pacc[mt][nt][r];
        }
  }
}

extern "C" void kernel_launch(void* const* d_in, const int* in_sizes, int n_in,
                              void* d_out, int out_size, void* d_ws, size_t ws_size,
                              hipStream_t stream) {
  const float* x      = (const float*)d_in[0];
  const float* norm_w = (const float*)d_in[1];
  const float* norm_b = (const float*)d_in[2];
  const float* qkv_w  = (const float*)d_in[3];
  const float* qkv_b  = (const float*)d_in[4];
  const float* proj_w = (const float*)d_in[5];
  const float* proj_b = (const float*)d_in[6];
  float* out   = (float*)d_out;
  float* stats = (float*)d_ws;                         // 1024*2 f32 = 8 KB
  short* wq    = (short*)((char*)d_ws + 8192);         // 384*128 bf16
  short* wp    = wq + 384 * 128;                       // 128*128 bf16
  float2* part = (float2*)((char*)d_ws + 139264);      // 8192 float2 = 64 KB

  hipLaunchKernelGGL(cvt_w_kernel, dim3(256), dim3(256), 0, stream, qkv_w, proj_w, wq);
  hipLaunchKernelGGL(ln_part_kernel, dim3(8192), dim3(256), 0, stream, x, part);
  hipLaunchKernelGGL(ln_final_kernel, dim3(4), dim3(256), 0, stream, part, stats);
  hipLaunchKernelGGL(win_attn_kernel, dim3(32 * 32 * B_), dim3(256), 0, stream,
                     x, stats, norm_w, norm_b, wq, qkv_b, wp, proj_b, out);
}